// Round 5
// baseline (273.987 us; speedup 1.0000x reference)
//
#include <hip/hip_runtime.h>

typedef unsigned short u16;
typedef unsigned int u32;
typedef __bf16 bf16x8 __attribute__((ext_vector_type(8)));
typedef float f32x4 __attribute__((ext_vector_type(4)));

#define N_NODES 10000
#define N_EDGES 160000
#define D_IN 512
#define D_HID 1024

#define AS1 __attribute__((address_space(1)))
#define AS3 __attribute__((address_space(3)))

__device__ __forceinline__ u16 f2bf(float f) {
    union { float f; u32 u; } v; v.f = f;
    return (u16)((v.u + 0x7fffu + ((v.u >> 16) & 1u)) >> 16);
}
__device__ __forceinline__ float b2f(u32 h) {
    union { u32 u; float f; } v; v.u = h << 16; return v.f;
}

// ---- CSR build: histogram of dst ----
__global__ void hist_k(const int* __restrict__ dst, int* __restrict__ counts) {
    int e = blockIdx.x * 256 + threadIdx.x;
    if (e < N_EDGES) atomicAdd(&counts[dst[e]], 1);
}

// ---- single-block scan via wave shuffles: offs[10001], cursor[10000] ----
__global__ __launch_bounds__(1024) void scan_k(const int* __restrict__ counts,
                                               int* __restrict__ offs,
                                               int* __restrict__ cursor) {
    __shared__ int wpre[16];
    int t = threadIdx.x, l = t & 63, w = t >> 6;
    int base = t * 10;
    int c[10];
    int lsum = 0;
#pragma unroll
    for (int i = 0; i < 10; i++) {
        int idx = base + i;
        c[i] = (idx < N_NODES) ? counts[idx] : 0;
        lsum += c[i];
    }
    int sc = lsum;
#pragma unroll
    for (int d = 1; d < 64; d <<= 1) {
        int v = __shfl_up(sc, d);
        if (l >= d) sc += v;
    }
    __shared__ int wsum[16];
    if (l == 63) wsum[w] = sc;
    __syncthreads();
    if (w == 0 && l < 16) {
        int v = wsum[l];
        int p = v;
#pragma unroll
        for (int d = 1; d < 16; d <<= 1) {
            int u = __shfl_up(p, d);
            if (l >= d) p += u;
        }
        wpre[l] = p - v;
    }
    __syncthreads();
    int run = wpre[w] + sc - lsum;
#pragma unroll
    for (int i = 0; i < 10; i++) {
        int idx = base + i;
        if (idx < N_NODES) { offs[idx] = run; cursor[idx] = run; run += c[i]; }
    }
    if (t == 1023) offs[N_NODES] = wpre[15] + sc;
}

// ---- reorder edges into dst-sorted order ----
__global__ void reorder_k(const int* __restrict__ src, const int* __restrict__ dst,
                          int* __restrict__ cursor, int* __restrict__ ssrc) {
    int e = blockIdx.x * 256 + threadIdx.x;
    if (e >= N_EDGES) return;
    int d = dst[e];
    int pos = atomicAdd(&cursor[d], 1);
    ssrc[pos] = src[e];
}

// ---- fp32 -> bf16 convert (feat copy), 8 elems/thread ----
__global__ void cvt_bf16_k(const float* __restrict__ in, u16* __restrict__ out, int n) {
    int i = (blockIdx.x * 256 + threadIdx.x) * 8;
    if (i >= n) return;
    float4 a = *(const float4*)(in + i);
    float4 b = *(const float4*)(in + i + 4);
    uint4 o;
    o.x = (u32)f2bf(a.x) | ((u32)f2bf(a.y) << 16);
    o.y = (u32)f2bf(a.z) | ((u32)f2bf(a.w) << 16);
    o.z = (u32)f2bf(b.x) | ((u32)f2bf(b.y) << 16);
    o.w = (u32)f2bf(b.z) | ((u32)f2bf(b.w) << 16);
    *(uint4*)(out + i) = o;
}

// ---- fused W1/W2 transpose+convert: WT[n][k] = bf16(W[k][n]) ----
__global__ void transw_k(const float* __restrict__ W1, u16* __restrict__ w1t,
                         const float* __restrict__ W2, u16* __restrict__ w2t) {
    __shared__ float tile[32][33];
    int b = blockIdx.x;
    const float* W; u16* WT; int K, N, nt;
    if (b < 512) { W = W1; WT = w1t; K = D_IN;  N = D_HID; nt = 32; }
    else         { b -= 512; W = W2; WT = w2t; K = D_HID; N = D_IN;  nt = 16; }
    int n0 = (b % nt) * 32, k0 = (b / nt) * 32;
    int tx = threadIdx.x, ty = threadIdx.y;
#pragma unroll
    for (int i = 0; i < 32; i += 8)
        tile[ty + i][tx] = W[(size_t)(k0 + ty + i) * N + n0 + tx];
    __syncthreads();
#pragma unroll
    for (int i = 0; i < 32; i += 8)
        WT[(size_t)(n0 + ty + i) * K + k0 + tx] = f2bf(tile[tx][ty + i]);
}

// ---- gather-sum from bf16 feat + (1+eps)*fp32 self, write bf16 ----
__global__ __launch_bounds__(128) void gather_k(const float* __restrict__ feat,
                                                const u16* __restrict__ featb,
                                                const float* __restrict__ eps,
                                                const int* __restrict__ offs,
                                                const int* __restrict__ ssrc,
                                                u16* __restrict__ out) {
    int n = (blockIdx.x * 128 + threadIdx.x) >> 6;
    int l = threadIdx.x & 63;
    if (n >= N_NODES) return;
    int beg = offs[n], end = offs[n + 1];
    float s = 1.0f + eps[0];
    float4 s0 = *(const float4*)(feat + (size_t)n * D_IN + l * 8);
    float4 s1 = *(const float4*)(feat + (size_t)n * D_IN + l * 8 + 4);
    float acc[8] = { s * s0.x, s * s0.y, s * s0.z, s * s0.w,
                     s * s1.x, s * s1.y, s * s1.z, s * s1.w };
    int e = beg;
    for (; e + 4 <= end; e += 4) {
        int i0 = ssrc[e], i1 = ssrc[e + 1], i2 = ssrc[e + 2], i3 = ssrc[e + 3];
        uint4 v0 = *(const uint4*)(featb + (size_t)i0 * D_IN + l * 8);
        uint4 v1 = *(const uint4*)(featb + (size_t)i1 * D_IN + l * 8);
        uint4 v2 = *(const uint4*)(featb + (size_t)i2 * D_IN + l * 8);
        uint4 v3 = *(const uint4*)(featb + (size_t)i3 * D_IN + l * 8);
#define ACC4(v) \
        acc[0] += b2f(v.x & 0xffffu); acc[1] += b2f(v.x >> 16); \
        acc[2] += b2f(v.y & 0xffffu); acc[3] += b2f(v.y >> 16); \
        acc[4] += b2f(v.z & 0xffffu); acc[5] += b2f(v.z >> 16); \
        acc[6] += b2f(v.w & 0xffffu); acc[7] += b2f(v.w >> 16);
        ACC4(v0) ACC4(v1) ACC4(v2) ACC4(v3)
    }
    for (; e < end; e++) {
        int i0 = ssrc[e];
        uint4 v0 = *(const uint4*)(featb + (size_t)i0 * D_IN + l * 8);
        ACC4(v0)
    }
#undef ACC4
    uint4 o;
    o.x = (u32)f2bf(acc[0]) | ((u32)f2bf(acc[1]) << 16);
    o.y = (u32)f2bf(acc[2]) | ((u32)f2bf(acc[3]) << 16);
    o.z = (u32)f2bf(acc[4]) | ((u32)f2bf(acc[5]) << 16);
    o.w = (u32)f2bf(acc[6]) | ((u32)f2bf(acc[7]) << 16);
    *(uint4*)(out + (size_t)n * D_IN + l * 8) = o;
}

// ---- GEMM: C[M,N] = A[M,K] @ B[K,N]; A bf16 row-major, BT bf16 [N,K] ----
// BARRIER-FREE K-loop:
//   * B weight stripe (64 cols x 512 K-chunk, +8 pad) resident in LDS, staged
//     once per chunk via global_load_lds + ONE barrier. 520-elem col stride
//     => <=2-way bank aliasing on frag reads (free, m136).
//   * A fragments load DIRECTLY global->VGPR (16B/lane contiguous), 3-slot
//     depth-2 software pipeline; B frags 2-slot depth-1 ds_read prefetch.
//   No __syncthreads in the steady state -> no vmcnt(0) drain; compiler emits
//   fine-grained vmcnt/lgkmcnt (the AITER-style loop at HIP level).
// Block: 128 rows x 64 cols, 4 waves 2x2 (each 64r x 32c), 16x16x32 MFMA.
// EPI=0: C = bf16(relu(acc + bias));  EPI=1: C = acc + bias + feat (fp32)
#define BCOL 64
#define KC 512
#define LDB 520   // KC + 8 pad
template <int EPI>
__global__ __launch_bounds__(256) void gemm_k(const u16* __restrict__ A,
                                              const u16* __restrict__ BT,
                                              const float* __restrict__ bias,
                                              const float* __restrict__ feat,
                                              void* __restrict__ Cout,
                                              int M, int N, int K) {
    __shared__ __bf16 sB[BCOL * LDB];   // 66,560 B
    const int row0 = blockIdx.y * 128;
    const int col0 = blockIdx.x * BCOL;
    const int t = threadIdx.x;
    const int w = t >> 6, l = t & 63;
    const int wm = (w >> 1) * 64;        // wave row offset in tile
    const int wn = (w & 1) * 32;         // wave col offset in stripe
    const int lr = l & 15;
    const int lq = l >> 4;

    // per-lane A fragment base pointers (row-tile i), k advances by +kk
    const u16* pa[4];
#pragma unroll
    for (int i = 0; i < 4; i++) {
        int r = row0 + wm + i * 16 + lr; if (r > M - 1) r = M - 1;
        pa[i] = A + (size_t)r * K + lq * 8;
    }

    f32x4 acc[4][2] = {};

    for (int kc = 0; kc < K; kc += KC) {
        if (kc) __syncthreads();   // chunk 2+: wait all waves done with prev B
        // stage B stripe chunk: wave w stages cols w*16..w*16+15; one
        // global_load_lds covers one col's full 512-K chunk (64 lanes x 16B)
#pragma unroll
        for (int ci = 0; ci < 16; ci++) {
            int c = w * 16 + ci;
            __builtin_amdgcn_global_load_lds(
                (const AS1 void*)(BT + (size_t)(col0 + c) * K + kc + l * 8),
                (AS3 void*)(sB + c * LDB), 16, 0, 0);
        }
        __syncthreads();

        bf16x8 fa[3][4];
        bf16x8 fbb[2][2];
#pragma unroll
        for (int i = 0; i < 4; i++) fa[0][i] = *(const bf16x8*)(pa[i] + kc);
#pragma unroll
        for (int i = 0; i < 4; i++) fa[1][i] = *(const bf16x8*)(pa[i] + kc + 32);
#pragma unroll
        for (int j = 0; j < 2; j++)
            fbb[0][j] = *(const bf16x8*)(sB + (wn + j * 16 + lr) * LDB + lq * 8);

#pragma unroll
        for (int s = 0; s < 16; s++) {
            if (s + 2 < 16) {
#pragma unroll
                for (int i = 0; i < 4; i++)
                    fa[(s + 2) % 3][i] = *(const bf16x8*)(pa[i] + kc + (s + 2) * 32);
            }
            if (s + 1 < 16) {
#pragma unroll
                for (int j = 0; j < 2; j++)
                    fbb[(s + 1) & 1][j] = *(const bf16x8*)(sB + (wn + j * 16 + lr) * LDB
                                                           + (s + 1) * 32 + lq * 8);
            }
#pragma unroll
            for (int i = 0; i < 4; i++)
#pragma unroll
                for (int j = 0; j < 2; j++)
                    acc[i][j] = __builtin_amdgcn_mfma_f32_16x16x32_bf16(
                        fa[s % 3][i], fbb[s & 1][j], acc[i][j], 0, 0, 0);
        }
    }

#pragma unroll
    for (int i = 0; i < 4; i++) {
        int rowb = row0 + wm + i * 16 + lq * 4;
#pragma unroll
        for (int j = 0; j < 2; j++) {
            int col = col0 + wn + j * 16 + lr;
            float bv = bias[col];
#pragma unroll
            for (int r = 0; r < 4; r++) {
                int rr = rowb + r;
                if (rr < M) {
                    float v = acc[i][j][r] + bv;
                    if (EPI == 0) {
                        v = fmaxf(v, 0.0f);
                        ((u16*)Cout)[(size_t)rr * N + col] = f2bf(v);
                    } else {
                        v += feat[(size_t)rr * N + col];
                        ((float*)Cout)[(size_t)rr * N + col] = v;
                    }
                }
            }
        }
    }
}

extern "C" void kernel_launch(void* const* d_in, const int* in_sizes, int n_in,
                              void* d_out, int out_size, void* d_ws, size_t ws_size,
                              hipStream_t stream) {
    const float* feat = (const float*)d_in[0];
    const float* W1   = (const float*)d_in[1];
    const float* b1   = (const float*)d_in[2];
    const float* W2   = (const float*)d_in[3];
    const float* b2   = (const float*)d_in[4];
    const float* eps  = (const float*)d_in[5];
    const int*   src  = (const int*)d_in[6];
    const int*   dst  = (const int*)d_in[7];
    float* out = (float*)d_out;

    char* ws = (char*)d_ws;
    u16* rst_b16 = (u16*)(ws);                        // 10,240,000 B
    u16* h_b16   = (u16*)(ws + 10240000);             // 20,480,000 B
    u16* featb   = (u16*)(ws + 30720000);             // 10,240,000 B
    u16* w1t     = (u16*)(ws + 40960000);             //  1,048,576 B
    u16* w2t     = (u16*)(ws + 42008576);             //  1,048,576 B
    int* counts  = (int*)(ws + 43057152);             //     40,000 B
    int* offs    = (int*)(ws + 43097152);             //     40,004 B
    int* cursor  = (int*)(ws + 43137160);             //     40,000 B
    int* ssrc    = (int*)(ws + 43177160);             //    640,000 B

    const int NE = N_NODES * D_IN;  // 5,120,000

    hipMemsetAsync(counts, 0, N_NODES * sizeof(int), stream);
    hist_k<<<(N_EDGES + 255) / 256, 256, 0, stream>>>(dst, counts);
    scan_k<<<1, 1024, 0, stream>>>(counts, offs, cursor);
    reorder_k<<<(N_EDGES + 255) / 256, 256, 0, stream>>>(src, dst, cursor, ssrc);

    cvt_bf16_k<<<NE / 8 / 256, 256, 0, stream>>>(feat, featb, NE);
    transw_k<<<1024, dim3(32, 8), 0, stream>>>(W1, w1t, W2, w2t);

    gather_k<<<(N_NODES + 1) / 2, 128, 0, stream>>>(feat, featb, eps, offs, ssrc, rst_b16);

    const int MT = (N_NODES + 127) / 128;  // 79
    gemm_k<0><<<dim3(D_HID / BCOL, MT), 256, 0, stream>>>(rst_b16, w1t, b1, nullptr,
                                                          (void*)h_b16, N_NODES, D_HID, D_IN);
    gemm_k<1><<<dim3(D_IN / BCOL, MT), 256, 0, stream>>>(h_b16, w2t, b2, feat,
                                                         (void*)out, N_NODES, D_IN, D_HID);
}